// Round 1
// baseline (472.939 us; speedup 1.0000x reference)
//
#include <hip/hip_runtime.h>
#include <hip/hip_bf16.h>

// Shapes: n=8, c=128, h=w=64, hw=4096, m=c*21=2688, groups=4
// ws layout (floats):
//  xpad (8,128,66,72)  = 4,866,048   x zero-padded: y+1, xx+3
//  t1   (8,128,4096)   = 4,194,304   p1_w * x
//  t2   (8,128,4096)   = 4,194,304   x + t1
//  t7p  (8,128,64,76)  = 4,980,736   t7 padded: xx+6
//  t11  (8,128,2688)   = 2,752,512
//  wft  (128,2688)     =   344,064   WfoldT[j][m]
//  upart(7,8,128,128)  =   917,504   split-K partials of U
//  U    (8,128,128)    =   131,072
// total 22,380,544 floats = 89.5 MB

__global__ void prep_kernel(const float* __restrict__ x, const float* __restrict__ p1,
                            float* __restrict__ t1, float* __restrict__ t2,
                            float* __restrict__ xpad) {
    int idx = blockIdx.x * 256 + threadIdx.x;      // < 4194304
    int xx = idx & 63;
    int y  = (idx >> 6) & 63;
    int ch = (idx >> 12) & 127;
    int n  = idx >> 19;
    float v = x[idx];
    float p = p1[ch * 64 + y];                     // p1_w shape (1,c,h,1)
    float a = p * v;
    t1[idx] = a;
    t2[idx] = v + a;
    xpad[((size_t)(n * 128 + ch) * 66 + (y + 1)) * 72 + xx + 3] = v;
}

// WfoldT[j][m] = (m/672 == j/32) ? p10[m*32 + (j%32)] : 0
__global__ void wft_kernel(const float* __restrict__ p10, float* __restrict__ wft) {
    int idx = blockIdx.x * 256 + threadIdx.x;      // < 344064
    int j = idx / 2688;
    int m = idx - j * 2688;
    float v = 0.0f;
    if ((m / 672) == (j >> 5)) v = p10[m * 32 + (j & 31)];
    wft[idx] = v;
}

// t7p[n][o][y][6+xx] = sum_c p7[o][c] * relu(x[n][c][y][xx])
__global__ __launch_bounds__(256) void t7_gemm(const float* __restrict__ x,
                                               const float* __restrict__ p7,
                                               float* __restrict__ t7p) {
    __shared__ __align__(16) float As[32][68];
    __shared__ __align__(16) float Bs[32][68];
    const int n  = blockIdx.z;
    const int o0 = blockIdx.y * 64;
    const int p0 = blockIdx.x * 64;
    const int t  = threadIdx.x;
    const int lr = t >> 2, lk = (t & 3) * 8;       // A loader: row o, k-offset
    const int bkk = t >> 3, bq = (t & 7) * 8;      // B loader: k row, p-offset
    const int tr = t >> 4, tc = t & 15;
    const float* xn = x + (size_t)n * 128 * 4096;
    float acc[4][4] = {};
    for (int k0 = 0; k0 < 128; k0 += 32) {
        float av[8], bv[8];
        const float* ap = p7 + (o0 + lr) * 128 + k0 + lk;
        const float* bp = xn + (size_t)(k0 + bkk) * 4096 + p0 + bq;
#pragma unroll
        for (int u = 0; u < 8; ++u) av[u] = ap[u];
#pragma unroll
        for (int u = 0; u < 8; ++u) bv[u] = fmaxf(bp[u], 0.0f);
        __syncthreads();
#pragma unroll
        for (int u = 0; u < 8; ++u) As[lk + u][lr] = av[u];
        *(float4*)&Bs[bkk][bq]     = make_float4(bv[0], bv[1], bv[2], bv[3]);
        *(float4*)&Bs[bkk][bq + 4] = make_float4(bv[4], bv[5], bv[6], bv[7]);
        __syncthreads();
#pragma unroll 8
        for (int kk = 0; kk < 32; ++kk) {
            float4 a4 = *(const float4*)&As[kk][tr * 4];
            float4 b4 = *(const float4*)&Bs[kk][tc * 4];
            float a[4] = {a4.x, a4.y, a4.z, a4.w};
            float b[4] = {b4.x, b4.y, b4.z, b4.w};
#pragma unroll
            for (int i = 0; i < 4; ++i)
#pragma unroll
                for (int j = 0; j < 4; ++j) acc[i][j] += a[i] * b[j];
        }
    }
    const int y = p0 >> 6;                          // p-tile is exactly one image row
#pragma unroll
    for (int i = 0; i < 4; ++i) {
        int o = o0 + tr * 4 + i;
        float* dst = t7p + ((size_t)(n * 128 + o) * 64 + y) * 76 + 6 + tc * 4;
#pragma unroll
        for (int j = 0; j < 4; ++j) dst[j] = acc[i][j];
    }
}

// out = t12 = x - 0.2 * sum_{j=0..4} t7p[.., xx+3j]
__global__ void t12_kernel(const float* __restrict__ x, const float* __restrict__ t7p,
                           float* __restrict__ out) {
    int idx = blockIdx.x * 256 + threadIdx.x;
    int xx = idx & 63;
    int rest = idx >> 6;                            // (n*128+ch)*64 + y
    const float* row = t7p + (size_t)rest * 76 + xx;
    float s = row[0] + row[3] + row[6] + row[9] + row[12];
    out[idx] = x[idx] - 0.2f * s;
}

// t11[n][c][m] = (1/64) * sum_p t1[n][c][p] * xpad[n][m/21][y+ki][xx+kj]
__global__ __launch_bounds__(256) void t11_gemm(const float* __restrict__ t1,
                                                const float* __restrict__ xpad,
                                                float* __restrict__ t11o) {
    __shared__ __align__(16) float As[32][68];
    __shared__ __align__(16) float Bs[32][68];
    const int n  = blockIdx.z;
    const int c0 = blockIdx.y * 64;
    const int m0 = blockIdx.x * 64;
    const int t  = threadIdx.x;
    const int lr = t >> 2, lk = (t & 3) * 8;
    const int tr = t >> 4, tc = t & 15;
    const int m   = m0 + lr;
    const int cp  = m / 21;
    const int rem = m - cp * 21;
    const int ki  = rem / 7;
    const int kj  = rem - ki * 7;
    const float* brow = xpad + ((size_t)(n * 128 + cp) * 66 + ki) * 72 + kj;
    const float* arow = t1 + (size_t)(n * 128 + c0 + lr) * 4096;
    float acc[4][4] = {};
    for (int p0 = 0; p0 < 4096; p0 += 32) {
        const int y = p0 >> 6, xx0 = p0 & 63;
        float av[8], bv[8];
        const float* ap = arow + p0 + lk;
        const float* bp = brow + y * 72 + xx0 + lk;
#pragma unroll
        for (int u = 0; u < 8; ++u) av[u] = ap[u];
#pragma unroll
        for (int u = 0; u < 8; ++u) bv[u] = bp[u];
        __syncthreads();
#pragma unroll
        for (int u = 0; u < 8; ++u) { As[lk + u][lr] = av[u]; Bs[lk + u][lr] = bv[u]; }
        __syncthreads();
#pragma unroll 8
        for (int kk = 0; kk < 32; ++kk) {
            float4 a4 = *(const float4*)&As[kk][tr * 4];
            float4 b4 = *(const float4*)&Bs[kk][tc * 4];
            float a[4] = {a4.x, a4.y, a4.z, a4.w};
            float b[4] = {b4.x, b4.y, b4.z, b4.w};
#pragma unroll
            for (int i = 0; i < 4; ++i)
#pragma unroll
                for (int j = 0; j < 4; ++j) acc[i][j] += a[i] * b[j];
        }
    }
#pragma unroll
    for (int i = 0; i < 4; ++i) {
        float* dst = t11o + (size_t)(n * 128 + c0 + tr * 4 + i) * 2688 + m0 + tc * 4;
#pragma unroll
        for (int j = 0; j < 4; ++j) dst[j] = acc[i][j] * 0.015625f;   // /sqrt(4096)
    }
}

// split-K: upart[seg][r][j] = sum_{m in seg} t11f[r][m] * wft[j][m]
__global__ __launch_bounds__(256) void u_gemm(const float* __restrict__ t11f,
                                              const float* __restrict__ wft,
                                              float* __restrict__ upart) {
    __shared__ __align__(16) float As[32][68];
    __shared__ __align__(16) float Bs[32][68];
    const int seg = blockIdx.z;                     // 0..6, 384 K each
    const int r0  = blockIdx.y * 64;                // row tile over n*c=1024
    const int j0  = blockIdx.x * 64;                // 0 or 64
    const int t   = threadIdx.x;
    const int lr = t >> 2, lk = (t & 3) * 8;
    const int tr = t >> 4, tc = t & 15;
    const float* arow = t11f + (size_t)(r0 + lr) * 2688;
    const float* brow = wft  + (size_t)(j0 + lr) * 2688;
    float acc[4][4] = {};
    for (int k0 = seg * 384; k0 < seg * 384 + 384; k0 += 32) {
        float av[8], bv[8];
#pragma unroll
        for (int u = 0; u < 8; ++u) av[u] = arow[k0 + lk + u];
#pragma unroll
        for (int u = 0; u < 8; ++u) bv[u] = brow[k0 + lk + u];
        __syncthreads();
#pragma unroll
        for (int u = 0; u < 8; ++u) { As[lk + u][lr] = av[u]; Bs[lk + u][lr] = bv[u]; }
        __syncthreads();
#pragma unroll 8
        for (int kk = 0; kk < 32; ++kk) {
            float4 a4 = *(const float4*)&As[kk][tr * 4];
            float4 b4 = *(const float4*)&Bs[kk][tc * 4];
            float a[4] = {a4.x, a4.y, a4.z, a4.w};
            float b[4] = {b4.x, b4.y, b4.z, b4.w};
#pragma unroll
            for (int i = 0; i < 4; ++i)
#pragma unroll
                for (int j = 0; j < 4; ++j) acc[i][j] += a[i] * b[j];
        }
    }
#pragma unroll
    for (int i = 0; i < 4; ++i) {
        float* dst = upart + ((size_t)seg * 1024 + r0 + tr * 4 + i) * 128 + j0 + tc * 4;
#pragma unroll
        for (int j = 0; j < 4; ++j) dst[j] = acc[i][j];
    }
}

__global__ void ureduce_kernel(const float* __restrict__ upart, float* __restrict__ U) {
    int idx = blockIdx.x * 256 + threadIdx.x;       // < 131072
    float s = 0.0f;
#pragma unroll
    for (int k = 0; k < 7; ++k) s += upart[(size_t)k * 131072 + idx];
    U[idx] = s;
}

// out = max(out, (1/sqrt(2688)) * sum_j U[n][c][j] * t2[n][j][p])
__global__ __launch_bounds__(256) void t13_gemm(const float* __restrict__ U,
                                                const float* __restrict__ t2,
                                                float* __restrict__ out) {
    __shared__ __align__(16) float As[32][68];
    __shared__ __align__(16) float Bs[32][68];
    const int n  = blockIdx.z;
    const int c0 = blockIdx.y * 64;
    const int p0 = blockIdx.x * 64;
    const int t  = threadIdx.x;
    const int lr = t >> 2, lk = (t & 3) * 8;
    const int bkk = t >> 3, bq = (t & 7) * 8;
    const int tr = t >> 4, tc = t & 15;
    float acc[4][4] = {};
    for (int k0 = 0; k0 < 128; k0 += 32) {
        float av[8], bv[8];
        const float* ap = U  + (size_t)(n * 128 + c0 + lr) * 128 + k0 + lk;
        const float* bp = t2 + (size_t)(n * 128 + k0 + bkk) * 4096 + p0 + bq;
#pragma unroll
        for (int u = 0; u < 8; ++u) av[u] = ap[u];
#pragma unroll
        for (int u = 0; u < 8; ++u) bv[u] = bp[u];
        __syncthreads();
#pragma unroll
        for (int u = 0; u < 8; ++u) As[lk + u][lr] = av[u];
        *(float4*)&Bs[bkk][bq]     = make_float4(bv[0], bv[1], bv[2], bv[3]);
        *(float4*)&Bs[bkk][bq + 4] = make_float4(bv[4], bv[5], bv[6], bv[7]);
        __syncthreads();
#pragma unroll 8
        for (int kk = 0; kk < 32; ++kk) {
            float4 a4 = *(const float4*)&As[kk][tr * 4];
            float4 b4 = *(const float4*)&Bs[kk][tc * 4];
            float a[4] = {a4.x, a4.y, a4.z, a4.w};
            float b[4] = {b4.x, b4.y, b4.z, b4.w};
#pragma unroll
            for (int i = 0; i < 4; ++i)
#pragma unroll
                for (int j = 0; j < 4; ++j) acc[i][j] += a[i] * b[j];
        }
    }
#pragma unroll
    for (int i = 0; i < 4; ++i) {
        size_t base = (size_t)(n * 128 + c0 + tr * 4 + i) * 4096 + p0 + tc * 4;
#pragma unroll
        for (int j = 0; j < 4; ++j) {
            float v = acc[i][j] * 0.0192879257f;    // 1/sqrt(2688)
            out[base + j] = fmaxf(out[base + j], v);
        }
    }
}

extern "C" void kernel_launch(void* const* d_in, const int* in_sizes, int n_in,
                              void* d_out, int out_size, void* d_ws, size_t ws_size,
                              hipStream_t stream) {
    const float* x   = (const float*)d_in[0];
    const float* p1  = (const float*)d_in[1];
    const float* p7  = (const float*)d_in[2];
    const float* p10 = (const float*)d_in[3];
    float* out = (float*)d_out;
    float* ws  = (float*)d_ws;

    float* xpad  = ws;
    float* t1    = xpad  + 4866048;
    float* t2    = t1    + 4194304;
    float* t7p   = t2    + 4194304;
    float* t11   = t7p   + 4980736;
    float* wft   = t11   + 2752512;
    float* upart = wft   + 344064;
    float* U     = upart + 917504;

    hipMemsetAsync(xpad, 0, (size_t)4866048 * 4, stream);
    hipMemsetAsync(t7p,  0, (size_t)4980736 * 4, stream);

    prep_kernel<<<16384, 256, 0, stream>>>(x, p1, t1, t2, xpad);
    wft_kernel<<<1344, 256, 0, stream>>>(p10, wft);
    t7_gemm<<<dim3(64, 2, 8), 256, 0, stream>>>(x, p7, t7p);
    t12_kernel<<<16384, 256, 0, stream>>>(x, t7p, out);
    t11_gemm<<<dim3(42, 2, 8), 256, 0, stream>>>(t1, xpad, t11);
    u_gemm<<<dim3(2, 16, 7), 256, 0, stream>>>(t11, wft, upart);
    ureduce_kernel<<<512, 256, 0, stream>>>(upart, U);
    t13_gemm<<<dim3(64, 2, 8), 256, 0, stream>>>(U, t2, out);
}

// Round 2
// 150.918 us; speedup vs baseline: 3.1337x; 3.1337x over previous
//
#include <hip/hip_runtime.h>
#include <hip/hip_bf16.h>

typedef unsigned short ushort_t;
typedef unsigned int uint_t;
typedef __attribute__((ext_vector_type(8))) short s16x8;
typedef __attribute__((ext_vector_type(4))) float f32x4;
typedef __attribute__((ext_vector_type(4))) uint_t u32x4;
typedef __attribute__((ext_vector_type(4))) ushort_t u16x4;

__device__ __forceinline__ ushort_t f2bf(float f) {
    uint_t u = __float_as_uint(f);
    uint_t r = (u + 0x7FFFu + ((u >> 16) & 1u)) >> 16;
    return (ushort_t)r;
}
__device__ __forceinline__ float bf2f(ushort_t u) {
    return __uint_as_float(((uint_t)u) << 16);
}

// ---- prep: t1h = bf16(p1*x), t2h = bf16(x + p1*x) ----
__global__ void prep4_kernel(const float* __restrict__ x, const float* __restrict__ p1,
                             ushort_t* __restrict__ t1h, ushort_t* __restrict__ t2h) {
    int idx4 = blockIdx.x * 256 + threadIdx.x;      // < 1,048,576
    int base = idx4 * 4;
    int y  = (base >> 6) & 63;
    int ch = (base >> 12) & 127;
    float4 v = *(const float4*)(x + base);
    float p = p1[ch * 64 + y];
    u16x4 o1, o2;
    float vv[4] = {v.x, v.y, v.z, v.w};
#pragma unroll
    for (int e = 0; e < 4; ++e) {
        float a = p * vv[e];
        o1[e] = f2bf(a);
        o2[e] = f2bf(vv[e] + a);
    }
    *(u16x4*)(t1h + base) = o1;
    *(u16x4*)(t2h + base) = o2;
}

// ---- xp parity buffers: xp_b[n][cp][yy(66)][xx'(72)] = xpad[yy][xx'+b] (bf16) ----
__global__ void xpgen_kernel(const float* __restrict__ x, ushort_t* __restrict__ xp) {
    int b = blockIdx.y;
    int i4 = blockIdx.x * 256 + threadIdx.x;        // < 1,216,512
    int i = i4 * 4;
    int nc = i / 4752;
    int rem = i - nc * 4752;
    int yy = rem / 72;
    int xxp = rem - yy * 72;
    int y = yy - 1;
    u16x4 o;
#pragma unroll
    for (int e = 0; e < 4; ++e) {
        int xi = xxp + e + b - 3;
        float v = (y >= 0 && y < 64 && xi >= 0 && xi < 64) ? x[(nc * 64 + y) * 64 + xi] : 0.0f;
        o[e] = f2bf(v);
    }
    *(u16x4*)(xp + (size_t)b * 4866048 + i) = o;
}

// WfoldT[j][m]
__global__ void wft_kernel(const float* __restrict__ p10, float* __restrict__ wft) {
    int idx = blockIdx.x * 256 + threadIdx.x;       // < 344064
    int j = idx / 2688;
    int m = idx - j * 2688;
    float v = 0.0f;
    if ((m / 672) == (j >> 5)) v = p10[m * 32 + (j & 31)];
    wft[idx] = v;
}

// t7p[n][o][y][6+xx] = sum_c p7[o][c] * relu(x[n][c][y][xx])   (fp32)
__global__ __launch_bounds__(256) void t7_gemm(const float* __restrict__ x,
                                               const float* __restrict__ p7,
                                               float* __restrict__ t7p) {
    __shared__ __align__(16) float As[32][68];
    __shared__ __align__(16) float Bs[32][68];
    const int n  = blockIdx.z;
    const int o0 = blockIdx.y * 64;
    const int p0 = blockIdx.x * 64;
    const int t  = threadIdx.x;
    const int lr = t >> 2, lk = (t & 3) * 8;
    const int bkk = t >> 3, bq = (t & 7) * 8;
    const int tr = t >> 4, tc = t & 15;
    const float* xn = x + (size_t)n * 128 * 4096;
    float acc[4][4] = {};
    for (int k0 = 0; k0 < 128; k0 += 32) {
        float av[8], bv[8];
        const float* ap = p7 + (o0 + lr) * 128 + k0 + lk;
        const float* bp = xn + (size_t)(k0 + bkk) * 4096 + p0 + bq;
#pragma unroll
        for (int u = 0; u < 8; ++u) av[u] = ap[u];
#pragma unroll
        for (int u = 0; u < 8; ++u) bv[u] = fmaxf(bp[u], 0.0f);
        __syncthreads();
#pragma unroll
        for (int u = 0; u < 8; ++u) As[lk + u][lr] = av[u];
        *(float4*)&Bs[bkk][bq]     = make_float4(bv[0], bv[1], bv[2], bv[3]);
        *(float4*)&Bs[bkk][bq + 4] = make_float4(bv[4], bv[5], bv[6], bv[7]);
        __syncthreads();
#pragma unroll 8
        for (int kk = 0; kk < 32; ++kk) {
            float4 a4 = *(const float4*)&As[kk][tr * 4];
            float4 b4 = *(const float4*)&Bs[kk][tc * 4];
            float a[4] = {a4.x, a4.y, a4.z, a4.w};
            float b[4] = {b4.x, b4.y, b4.z, b4.w};
#pragma unroll
            for (int i = 0; i < 4; ++i)
#pragma unroll
                for (int j = 0; j < 4; ++j) acc[i][j] += a[i] * b[j];
        }
    }
    const int y = p0 >> 6;
#pragma unroll
    for (int i = 0; i < 4; ++i) {
        int o = o0 + tr * 4 + i;
        float* dst = t7p + ((size_t)(n * 128 + o) * 64 + y) * 76 + 6 + tc * 4;
#pragma unroll
        for (int j = 0; j < 4; ++j) dst[j] = acc[i][j];
    }
}

// out = t12 = x - 0.2 * sum_{j=0..4} t7p[.., xx+3j]
__global__ void t12_kernel(const float* __restrict__ x, const float* __restrict__ t7p,
                           float* __restrict__ out) {
    int idx = blockIdx.x * 256 + threadIdx.x;
    int xx = idx & 63;
    int rest = idx >> 6;
    const float* row = t7p + (size_t)rest * 76 + xx;
    float s = row[0] + row[3] + row[6] + row[9] + row[12];
    out[idx] = x[idx] - 0.2f * s;
}

// ---- t11 via bf16 MFMA: C[c][m] = (1/64) sum_p t1[c][p] * Bm[m][p], split-K=3 ----
__global__ __launch_bounds__(256) void t11_mfma(const ushort_t* __restrict__ t1h,
                                                const ushort_t* __restrict__ xp,
                                                float* __restrict__ t11p) {
    __shared__ ushort_t As[128 * 64];
    __shared__ ushort_t Bs[128 * 64];
    const int m0 = blockIdx.x * 128;
    const int s  = blockIdx.y;
    const int n  = blockIdx.z;
    const int tid = threadIdx.x;
    const int lane = tid & 63, wid = tid >> 6;
    const int wr = wid >> 1, wc = wid & 1;
    const int kbeg = s * 1344;
    const int kend = (s == 2) ? 4096 : kbeg + 1344;
    const int y0 = kbeg >> 6;

    const ushort_t* aPtr[4];
    const uint_t*   bPtr[4];
    int off[4];
#pragma unroll
    for (int r = 0; r < 4; ++r) {
        int slot = r * 256 + tid;
        int row = slot >> 3, ch = slot & 7;
        off[r] = (row * 8 + (ch ^ (row & 7))) * 8;
        aPtr[r] = t1h + (size_t)(n * 128 + row) * 4096 + kbeg + ch * 8;
        int m = m0 + row;
        int cp = m / 21, rem = m - cp * 21;
        int ki = rem / 7, kj = rem - ki * 7;
        int a2 = kj >> 1, bpar = kj & 1;
        bPtr[r] = (const uint_t*)(xp + (size_t)bpar * 4866048 +
                                  ((size_t)(n * 128 + cp) * 66 + y0 + ki) * 72 + 2 * a2 + ch * 8);
    }

    const int q = lane >> 4, fr = lane & 15;
    int aRd[2][4], bRd[2][4];
#pragma unroll
    for (int i = 0; i < 4; ++i) {
        int ra = wr * 64 + i * 16 + fr;
        int rb = wc * 64 + i * 16 + fr;
#pragma unroll
        for (int ks = 0; ks < 2; ++ks) {
            aRd[ks][i] = (ra * 8 + ((ks * 4 + q) ^ (ra & 7))) * 8;
            bRd[ks][i] = (rb * 8 + ((ks * 4 + q) ^ (rb & 7))) * 8;
        }
    }

    f32x4 acc[4][4] = {};
    const int nsteps = (kend - kbeg) >> 6;
    for (int t = 0; t < nsteps; ++t) {
        s16x8 av[4];
        u32x4 bv[4];
#pragma unroll
        for (int r = 0; r < 4; ++r) {
            av[r] = *(const s16x8*)aPtr[r];
            const uint_t* p = bPtr[r];
            bv[r] = (u32x4){p[0], p[1], p[2], p[3]};
            aPtr[r] += 64;
            bPtr[r] += 36;
        }
        __syncthreads();
#pragma unroll
        for (int r = 0; r < 4; ++r) {
            *(s16x8*)&As[off[r]] = av[r];
            *(u32x4*)&Bs[off[r]] = bv[r];
        }
        __syncthreads();
#pragma unroll
        for (int ks = 0; ks < 2; ++ks) {
            s16x8 a[4], b[4];
#pragma unroll
            for (int i = 0; i < 4; ++i) a[i] = *(const s16x8*)&As[aRd[ks][i]];
#pragma unroll
            for (int i = 0; i < 4; ++i) b[i] = *(const s16x8*)&Bs[bRd[ks][i]];
#pragma unroll
            for (int i = 0; i < 4; ++i)
#pragma unroll
                for (int j = 0; j < 4; ++j)
                    acc[i][j] = __builtin_amdgcn_mfma_f32_16x16x32_bf16(a[i], b[j], acc[i][j], 0, 0, 0);
        }
    }

    const float scale = 0.015625f;   // 1/64
#pragma unroll
    for (int i = 0; i < 4; ++i) {
        int row = wr * 64 + i * 16 + q * 4;
#pragma unroll
        for (int j = 0; j < 4; ++j) {
            int col = m0 + wc * 64 + j * 16 + fr;
            float* dp = t11p + (size_t)s * 2752512 + (size_t)(n * 128 + row) * 2688 + col;
#pragma unroll
            for (int reg = 0; reg < 4; ++reg)
                dp[(size_t)reg * 2688] = acc[i][j][reg] * scale;
        }
    }
}

// split: upart[z][r][j] = sum_{m in seg} t11p[sp][r][m] * wft[j][m],  z=(sp,mseg)
__global__ __launch_bounds__(256) void u_gemm(const float* __restrict__ t11p,
                                              const float* __restrict__ wft,
                                              float* __restrict__ upart) {
    __shared__ __align__(16) float As[32][68];
    __shared__ __align__(16) float Bs[32][68];
    const int z   = blockIdx.z;                     // 0..20
    const int sp  = z / 7, mseg = z - sp * 7;
    const int r0  = blockIdx.y * 64;
    const int j0  = blockIdx.x * 64;
    const int t   = threadIdx.x;
    const int lr = t >> 2, lk = (t & 3) * 8;
    const int tr = t >> 4, tc = t & 15;
    const float* arow = t11p + (size_t)sp * 2752512 + (size_t)(r0 + lr) * 2688;
    const float* brow = wft + (size_t)(j0 + lr) * 2688;
    float acc[4][4] = {};
    for (int k0 = mseg * 384; k0 < mseg * 384 + 384; k0 += 32) {
        float av[8], bv[8];
#pragma unroll
        for (int u = 0; u < 8; ++u) av[u] = arow[k0 + lk + u];
#pragma unroll
        for (int u = 0; u < 8; ++u) bv[u] = brow[k0 + lk + u];
        __syncthreads();
#pragma unroll
        for (int u = 0; u < 8; ++u) { As[lk + u][lr] = av[u]; Bs[lk + u][lr] = bv[u]; }
        __syncthreads();
#pragma unroll 8
        for (int kk = 0; kk < 32; ++kk) {
            float4 a4 = *(const float4*)&As[kk][tr * 4];
            float4 b4 = *(const float4*)&Bs[kk][tc * 4];
            float a[4] = {a4.x, a4.y, a4.z, a4.w};
            float b[4] = {b4.x, b4.y, b4.z, b4.w};
#pragma unroll
            for (int i = 0; i < 4; ++i)
#pragma unroll
                for (int j = 0; j < 4; ++j) acc[i][j] += a[i] * b[j];
        }
    }
#pragma unroll
    for (int i = 0; i < 4; ++i) {
        float* dst = upart + ((size_t)z * 1024 + r0 + tr * 4 + i) * 128 + j0 + tc * 4;
#pragma unroll
        for (int j = 0; j < 4; ++j) dst[j] = acc[i][j];
    }
}

__global__ void ureduce_kernel(const float* __restrict__ upart, float* __restrict__ U) {
    int idx = blockIdx.x * 256 + threadIdx.x;       // < 131072
    float s = 0.0f;
#pragma unroll
    for (int k = 0; k < 21; ++k) s += upart[(size_t)k * 131072 + idx];
    U[idx] = s;
}

// out = max(out, (1/sqrt(2688)) * sum_j U[n][c][j] * t2h[n][j][p])
__global__ __launch_bounds__(256) void t13_gemm(const float* __restrict__ U,
                                                const ushort_t* __restrict__ t2h,
                                                float* __restrict__ out) {
    __shared__ __align__(16) float As[32][68];
    __shared__ __align__(16) float Bs[32][68];
    const int n  = blockIdx.z;
    const int c0 = blockIdx.y * 64;
    const int p0 = blockIdx.x * 64;
    const int t  = threadIdx.x;
    const int lr = t >> 2, lk = (t & 3) * 8;
    const int bkk = t >> 3, bq = (t & 7) * 8;
    const int tr = t >> 4, tc = t & 15;
    float acc[4][4] = {};
    for (int k0 = 0; k0 < 128; k0 += 32) {
        float av[8], bv[8];
        const float* ap = U + (size_t)(n * 128 + c0 + lr) * 128 + k0 + lk;
        const ushort_t* bp = t2h + (size_t)(n * 128 + k0 + bkk) * 4096 + p0 + bq;
#pragma unroll
        for (int u = 0; u < 8; ++u) av[u] = ap[u];
#pragma unroll
        for (int u = 0; u < 8; ++u) bv[u] = bf2f(bp[u]);
        __syncthreads();
#pragma unroll
        for (int u = 0; u < 8; ++u) As[lk + u][lr] = av[u];
        *(float4*)&Bs[bkk][bq]     = make_float4(bv[0], bv[1], bv[2], bv[3]);
        *(float4*)&Bs[bkk][bq + 4] = make_float4(bv[4], bv[5], bv[6], bv[7]);
        __syncthreads();
#pragma unroll 8
        for (int kk = 0; kk < 32; ++kk) {
            float4 a4 = *(const float4*)&As[kk][tr * 4];
            float4 b4 = *(const float4*)&Bs[kk][tc * 4];
            float a[4] = {a4.x, a4.y, a4.z, a4.w};
            float b[4] = {b4.x, b4.y, b4.z, b4.w};
#pragma unroll
            for (int i = 0; i < 4; ++i)
#pragma unroll
                for (int j = 0; j < 4; ++j) acc[i][j] += a[i] * b[j];
        }
    }
#pragma unroll
    for (int i = 0; i < 4; ++i) {
        size_t base = (size_t)(n * 128 + c0 + tr * 4 + i) * 4096 + p0 + tc * 4;
#pragma unroll
        for (int j = 0; j < 4; ++j) {
            float v = acc[i][j] * 0.0192879257f;
            out[base + j] = fmaxf(out[base + j], v);
        }
    }
}

extern "C" void kernel_launch(void* const* d_in, const int* in_sizes, int n_in,
                              void* d_out, int out_size, void* d_ws, size_t ws_size,
                              hipStream_t stream) {
    const float* x   = (const float*)d_in[0];
    const float* p1  = (const float*)d_in[1];
    const float* p7  = (const float*)d_in[2];
    const float* p10 = (const float*)d_in[3];
    float* out = (float*)d_out;

    ushort_t* t2h = (ushort_t*)d_ws;                // 4,194,304 ushorts
    ushort_t* t1h = t2h + 4194304;                  // 4,194,304
    ushort_t* xp  = t1h + 4194304;                  // 9,732,096 (xp0|xp1)
    float* wft   = (float*)(xp + 9732096);          // 344,064 f
    float* E     = wft + 344064;                    // shared region
    float* t7p   = E;                               // 4,980,736 f
    float* t11p  = E;                               // 8,257,536 f (after t12)
    float* upart = E + 8257536;                     // 2,752,512 f
    float* U     = upart + 2752512;                 // 131,072 f

    hipMemsetAsync(t7p, 0, (size_t)4980736 * 4, stream);

    prep4_kernel<<<4096, 256, 0, stream>>>(x, p1, t1h, t2h);
    xpgen_kernel<<<dim3(4752, 2), 256, 0, stream>>>(x, xp);
    wft_kernel<<<1344, 256, 0, stream>>>(p10, wft);
    t7_gemm<<<dim3(64, 2, 8), 256, 0, stream>>>(x, p7, t7p);
    t12_kernel<<<16384, 256, 0, stream>>>(x, t7p, out);
    t11_mfma<<<dim3(21, 3, 8), 256, 0, stream>>>(t1h, xp, t11p);
    u_gemm<<<dim3(2, 16, 21), 256, 0, stream>>>(t11p, wft, upart);
    ureduce_kernel<<<512, 256, 0, stream>>>(upart, U);
    t13_gemm<<<dim3(64, 2, 8), 256, 0, stream>>>(U, t2h, out);
}

// Round 3
// 138.873 us; speedup vs baseline: 3.4056x; 1.0867x over previous
//
#include <hip/hip_runtime.h>
#include <hip/hip_bf16.h>

typedef unsigned short ushort_t;
typedef unsigned int uint_t;
typedef __attribute__((ext_vector_type(8))) short s16x8;
typedef __attribute__((ext_vector_type(4))) float f32x4;
typedef __attribute__((ext_vector_type(4))) uint_t u32x4;
typedef __attribute__((ext_vector_type(4))) ushort_t u16x4;
typedef __attribute__((ext_vector_type(8))) ushort_t u16x8;

__device__ __forceinline__ ushort_t f2bf(float f) {
    uint_t u = __float_as_uint(f);
    uint_t r = (u + 0x7FFFu + ((u >> 16) & 1u)) >> 16;
    return (ushort_t)r;
}
__device__ __forceinline__ float bf2f(ushort_t u) {
    return __uint_as_float(((uint_t)u) << 16);
}

// ---- prep: t1h[c][p] (bf16), xTr[p][c] = relu(x) bf16, t2T[p][c] = x+p1*x bf16 ----
// grid (64 y, 2 ctile, 8 n), 256 thr. Tile = 64c x 64x (one image row y).
__global__ __launch_bounds__(256) void xtr_prep(const float* __restrict__ x,
                                                const float* __restrict__ p1,
                                                ushort_t* __restrict__ t1h,
                                                ushort_t* __restrict__ xTr,
                                                ushort_t* __restrict__ t2T) {
    __shared__ float xs[64][65];
    __shared__ float p1s[64];
    const int y  = blockIdx.x;
    const int c0 = blockIdx.y * 64;
    const int n  = blockIdx.z;
    const int t  = threadIdx.x;
    if (t < 64) p1s[t] = p1[(c0 + t) * 64 + y];
#pragma unroll
    for (int cc = 0; cc < 4; ++cc) {
        int c = cc * 16 + (t >> 4);
        int px = (t & 15) * 4;
        float4 v = *(const float4*)(x + ((size_t)((n * 128 + c0 + c)) * 64 + y) * 64 + px);
        xs[c][px] = v.x; xs[c][px + 1] = v.y; xs[c][px + 2] = v.z; xs[c][px + 3] = v.w;
    }
    __syncthreads();
    // t1h natural layout
    {
        int c = t >> 2, px0 = (t & 3) * 16;
        float pv = p1s[c];
        u16x8 o0, o1;
#pragma unroll
        for (int e = 0; e < 8; ++e) {
            o0[e] = f2bf(pv * xs[c][px0 + e]);
            o1[e] = f2bf(pv * xs[c][px0 + 8 + e]);
        }
        ushort_t* dst = t1h + (size_t)(n * 128 + c0 + c) * 4096 + y * 64 + px0;
        *(u16x8*)dst = o0;
        *(u16x8*)(dst + 8) = o1;
    }
    // transposed outputs
    {
        int p = t >> 2, cx0 = (t & 3) * 16;
        u16x8 r0, r1, s0, s1;
#pragma unroll
        for (int e = 0; e < 8; ++e) {
            float v0 = xs[cx0 + e][p];
            float v1 = xs[cx0 + 8 + e][p];
            r0[e] = f2bf(fmaxf(v0, 0.0f));
            r1[e] = f2bf(fmaxf(v1, 0.0f));
            s0[e] = f2bf(v0 + p1s[cx0 + e] * v0);
            s1[e] = f2bf(v1 + p1s[cx0 + 8 + e] * v1);
        }
        size_t base = ((size_t)n * 4096 + y * 64 + p) * 128 + c0 + cx0;
        *(u16x8*)(xTr + base) = r0;
        *(u16x8*)(xTr + base + 8) = r1;
        *(u16x8*)(t2T + base) = s0;
        *(u16x8*)(t2T + base + 8) = s1;
    }
}

// ---- xp parity buffers for t11 B ----
__global__ void xpgen_kernel(const float* __restrict__ x, ushort_t* __restrict__ xp) {
    int b = blockIdx.y;
    int i4 = blockIdx.x * 256 + threadIdx.x;
    int i = i4 * 4;
    int nc = i / 4752;
    int rem = i - nc * 4752;
    int yy = rem / 72;
    int xxp = rem - yy * 72;
    int y = yy - 1;
    u16x4 o;
#pragma unroll
    for (int e = 0; e < 4; ++e) {
        int xi = xxp + e + b - 3;
        float v = (y >= 0 && y < 64 && xi >= 0 && xi < 64) ? x[(nc * 64 + y) * 64 + xi] : 0.0f;
        o[e] = f2bf(v);
    }
    *(u16x4*)(xp + (size_t)b * 4866048 + i) = o;
}

// WfoldT[j][m] (fp32, block-diagonal)
__global__ void wft_kernel(const float* __restrict__ p10, float* __restrict__ wft) {
    int idx = blockIdx.x * 256 + threadIdx.x;       // < 344064
    int j = idx / 2688;
    int m = idx - j * 2688;
    float v = 0.0f;
    if ((m / 672) == (j >> 5)) v = p10[m * 32 + (j & 31)];
    wft[idx] = v;
}

__global__ void pcast_kernel(const float* __restrict__ p7, ushort_t* __restrict__ p7h) {
    int i = (blockIdx.x * 256 + threadIdx.x) * 4;   // < 16384
    float4 v = *(const float4*)(p7 + i);
    u16x4 o; o[0] = f2bf(v.x); o[1] = f2bf(v.y); o[2] = f2bf(v.z); o[3] = f2bf(v.w);
    *(u16x4*)(p7h + i) = o;
}

// ---- fused t7 (MFMA) + t12 epilogue: out = x - 0.2*sum_{j} t7[.., xx+3j-6] ----
// tile: M=128 (o), N=128 (p = 2 image rows), K=128 (c). grid (32 ptiles, 8 n).
__global__ __launch_bounds__(256) void t7t12_mfma(const ushort_t* __restrict__ p7h,
                                                  const ushort_t* __restrict__ xTr,
                                                  const float* __restrict__ x,
                                                  float* __restrict__ out) {
    __shared__ ushort_t sh[16384];                  // As | Bs, reused as Cs
    ushort_t* As = sh;
    ushort_t* Bs = sh + 8192;
    const int p0 = blockIdx.x * 128;
    const int n  = blockIdx.y;
    const int tid = threadIdx.x;
    const int lane = tid & 63, wid = tid >> 6;
    const int wr = wid >> 1, wc = wid & 1;

    const ushort_t* aPtr[4];
    const ushort_t* bPtr[4];
    int off[4];
#pragma unroll
    for (int r = 0; r < 4; ++r) {
        int slot = r * 256 + tid;
        int row = slot >> 3, ch = slot & 7;
        off[r] = (row * 8 + (ch ^ (row & 7))) * 8;
        aPtr[r] = p7h + row * 128 + ch * 8;
        bPtr[r] = xTr + ((size_t)n * 4096 + p0 + row) * 128 + ch * 8;
    }
    const int q = lane >> 4, fr = lane & 15;
    int aRd[2][4], bRd[2][4];
#pragma unroll
    for (int i = 0; i < 4; ++i) {
        int ra = wr * 64 + i * 16 + fr;
        int rb = wc * 64 + i * 16 + fr;
#pragma unroll
        for (int ks = 0; ks < 2; ++ks) {
            aRd[ks][i] = (ra * 8 + ((ks * 4 + q) ^ (ra & 7))) * 8;
            bRd[ks][i] = (rb * 8 + ((ks * 4 + q) ^ (rb & 7))) * 8;
        }
    }
    f32x4 acc[4][4] = {};
    for (int t = 0; t < 2; ++t) {
        s16x8 av[4], bv[4];
#pragma unroll
        for (int r = 0; r < 4; ++r) {
            av[r] = *(const s16x8*)aPtr[r];
            bv[r] = *(const s16x8*)bPtr[r];
            aPtr[r] += 64;
            bPtr[r] += 64;
        }
        __syncthreads();
#pragma unroll
        for (int r = 0; r < 4; ++r) {
            *(s16x8*)&As[off[r]] = av[r];
            *(s16x8*)&Bs[off[r]] = bv[r];
        }
        __syncthreads();
#pragma unroll
        for (int ks = 0; ks < 2; ++ks) {
            s16x8 a[4], b[4];
#pragma unroll
            for (int i = 0; i < 4; ++i) a[i] = *(const s16x8*)&As[aRd[ks][i]];
#pragma unroll
            for (int i = 0; i < 4; ++i) b[i] = *(const s16x8*)&Bs[bRd[ks][i]];
#pragma unroll
            for (int i = 0; i < 4; ++i)
#pragma unroll
                for (int j = 0; j < 4; ++j)
                    acc[i][j] = __builtin_amdgcn_mfma_f32_16x16x32_bf16(a[i], b[j], acc[i][j], 0, 0, 0);
        }
    }
    // epilogue: two passes over o-halves; Cs = 64 rows x 156 (2 sub-rows x 78, halo 6 each side)
    ushort_t* Cs = sh;
    for (int pass = 0; pass < 2; ++pass) {
        __syncthreads();
        for (int i2 = tid; i2 < 4992; i2 += 256) ((uint_t*)Cs)[i2] = 0u;
        __syncthreads();
        if (wr == pass) {
#pragma unroll
            for (int i = 0; i < 4; ++i) {
                int row = i * 16 + q * 4;
#pragma unroll
                for (int j = 0; j < 4; ++j) {
                    int col = wc * 64 + j * 16 + fr;
                    int cbase = (col >> 6) * 78 + 6 + (col & 63);
#pragma unroll
                    for (int reg = 0; reg < 4; ++reg)
                        Cs[(row + reg) * 156 + cbase] = f2bf(acc[i][j][reg]);
                }
            }
        }
        __syncthreads();
        for (int rep = 0; rep < 32; ++rep) {
            int flat = rep * 256 + tid;
            int ol = flat >> 7;                     // 0..63
            int pcol = flat & 127;
            int half = pcol >> 6, xx = pcol & 63;
            float s = 0.0f;
#pragma unroll
            for (int jj = 0; jj < 5; ++jj)
                s += bf2f(Cs[ol * 156 + half * 78 + xx + 3 * jj]);
            size_t oi = ((size_t)(n * 128 + pass * 64 + ol)) * 4096 + p0 + pcol;
            out[oi] = x[oi] - 0.2f * s;
        }
    }
}

// ---- t11 via bf16 MFMA, split-K=3, bf16 output ----
__global__ __launch_bounds__(256) void t11_mfma(const ushort_t* __restrict__ t1h,
                                                const ushort_t* __restrict__ xp,
                                                ushort_t* __restrict__ t11h) {
    __shared__ ushort_t As[128 * 64];
    __shared__ ushort_t Bs[128 * 64];
    const int m0 = blockIdx.x * 128;
    const int s  = blockIdx.y;
    const int n  = blockIdx.z;
    const int tid = threadIdx.x;
    const int lane = tid & 63, wid = tid >> 6;
    const int wr = wid >> 1, wc = wid & 1;
    const int kbeg = s * 1344;
    const int kend = (s == 2) ? 4096 : kbeg + 1344;
    const int y0 = kbeg >> 6;

    const ushort_t* aPtr[4];
    const uint_t*   bPtr[4];
    int off[4];
#pragma unroll
    for (int r = 0; r < 4; ++r) {
        int slot = r * 256 + tid;
        int row = slot >> 3, ch = slot & 7;
        off[r] = (row * 8 + (ch ^ (row & 7))) * 8;
        aPtr[r] = t1h + (size_t)(n * 128 + row) * 4096 + kbeg + ch * 8;
        int m = m0 + row;
        int cp = m / 21, rem = m - cp * 21;
        int ki = rem / 7, kj = rem - ki * 7;
        int a2 = kj >> 1, bpar = kj & 1;
        bPtr[r] = (const uint_t*)(xp + (size_t)bpar * 4866048 +
                                  ((size_t)(n * 128 + cp) * 66 + y0 + ki) * 72 + 2 * a2 + ch * 8);
    }
    const int q = lane >> 4, fr = lane & 15;
    int aRd[2][4], bRd[2][4];
#pragma unroll
    for (int i = 0; i < 4; ++i) {
        int ra = wr * 64 + i * 16 + fr;
        int rb = wc * 64 + i * 16 + fr;
#pragma unroll
        for (int ks = 0; ks < 2; ++ks) {
            aRd[ks][i] = (ra * 8 + ((ks * 4 + q) ^ (ra & 7))) * 8;
            bRd[ks][i] = (rb * 8 + ((ks * 4 + q) ^ (rb & 7))) * 8;
        }
    }
    f32x4 acc[4][4] = {};
    const int nsteps = (kend - kbeg) >> 6;
    for (int t = 0; t < nsteps; ++t) {
        s16x8 av[4];
        u32x4 bv[4];
#pragma unroll
        for (int r = 0; r < 4; ++r) {
            av[r] = *(const s16x8*)aPtr[r];
            const uint_t* p = bPtr[r];
            bv[r] = (u32x4){p[0], p[1], p[2], p[3]};
            aPtr[r] += 64;
            bPtr[r] += 36;
        }
        __syncthreads();
#pragma unroll
        for (int r = 0; r < 4; ++r) {
            *(s16x8*)&As[off[r]] = av[r];
            *(u32x4*)&Bs[off[r]] = bv[r];
        }
        __syncthreads();
#pragma unroll
        for (int ks = 0; ks < 2; ++ks) {
            s16x8 a[4], b[4];
#pragma unroll
            for (int i = 0; i < 4; ++i) a[i] = *(const s16x8*)&As[aRd[ks][i]];
#pragma unroll
            for (int i = 0; i < 4; ++i) b[i] = *(const s16x8*)&Bs[bRd[ks][i]];
#pragma unroll
            for (int i = 0; i < 4; ++i)
#pragma unroll
                for (int j = 0; j < 4; ++j)
                    acc[i][j] = __builtin_amdgcn_mfma_f32_16x16x32_bf16(a[i], b[j], acc[i][j], 0, 0, 0);
        }
    }
    const float scale = 0.015625f;   // 1/64
#pragma unroll
    for (int i = 0; i < 4; ++i) {
        int row = wr * 64 + i * 16 + q * 4;
#pragma unroll
        for (int j = 0; j < 4; ++j) {
            int col = m0 + wc * 64 + j * 16 + fr;
            ushort_t* dp = t11h + (size_t)s * 2752512 + (size_t)(n * 128 + row) * 2688 + col;
#pragma unroll
            for (int reg = 0; reg < 4; ++reg)
                dp[(size_t)reg * 2688] = f2bf(acc[i][j][reg] * scale);
        }
    }
}

// ---- U: block-sparse fold, fused over 3 split-K copies. grid (4 groups, 64 rtiles) ----
// Uh[r][j] = bf16( sum_sp sum_{m in group} t11h[sp][r][m] * wft[j][m] )
__global__ __launch_bounds__(256) void u_gemm_sparse(const ushort_t* __restrict__ t11h,
                                                     const float* __restrict__ wft,
                                                     ushort_t* __restrict__ Uh) {
    __shared__ float As[32][20];
    __shared__ float Bs[32][36];
    const int g  = blockIdx.x;
    const int r0 = blockIdx.y * 16;
    const int t  = threadIdx.x;
    const int rowA = t >> 4, kk2 = (t & 15) * 2;
    const int rowB = t >> 3, kk4 = (t & 7) * 4;
    const int tr = t >> 4, tc = t & 15;
    float acc0 = 0.0f, acc1 = 0.0f;
    for (int sp = 0; sp < 3; ++sp) {
        const ushort_t* arow = t11h + (size_t)sp * 2752512 + (size_t)(r0 + rowA) * 2688;
        const float*    brow = wft + (size_t)(g * 32 + rowB) * 2688;
        for (int k0 = g * 672; k0 < g * 672 + 672; k0 += 32) {
            uint_t av = *(const uint_t*)(arow + k0 + kk2);
            float4 bv = *(const float4*)(brow + k0 + kk4);
            __syncthreads();
            As[kk2][rowA]     = bf2f((ushort_t)(av & 0xFFFFu));
            As[kk2 + 1][rowA] = bf2f((ushort_t)(av >> 16));
            Bs[kk4][rowB] = bv.x; Bs[kk4 + 1][rowB] = bv.y;
            Bs[kk4 + 2][rowB] = bv.z; Bs[kk4 + 3][rowB] = bv.w;
            __syncthreads();
#pragma unroll 8
            for (int kk = 0; kk < 32; ++kk) {
                float a = As[kk][tr];
                acc0 += a * Bs[kk][tc * 2];
                acc1 += a * Bs[kk][tc * 2 + 1];
            }
        }
    }
    uint_t packed = (uint_t)f2bf(acc0) | ((uint_t)f2bf(acc1) << 16);
    *(uint_t*)&Uh[(size_t)(r0 + tr) * 128 + g * 32 + tc * 2] = packed;
}

// ---- t13: out = max(out, scale * Uh . t2T^T) via MFMA. grid (32 ptiles, 8 n) ----
__global__ __launch_bounds__(256) void t13_mfma(const ushort_t* __restrict__ Uh,
                                                const ushort_t* __restrict__ t2T,
                                                float* __restrict__ out) {
    __shared__ ushort_t As[8192];
    __shared__ ushort_t Bs[8192];
    const int p0 = blockIdx.x * 128;
    const int n  = blockIdx.y;
    const int tid = threadIdx.x;
    const int lane = tid & 63, wid = tid >> 6;
    const int wr = wid >> 1, wc = wid & 1;
    const ushort_t* aPtr[4];
    const ushort_t* bPtr[4];
    int off[4];
#pragma unroll
    for (int r = 0; r < 4; ++r) {
        int slot = r * 256 + tid;
        int row = slot >> 3, ch = slot & 7;
        off[r] = (row * 8 + (ch ^ (row & 7))) * 8;
        aPtr[r] = Uh + ((size_t)n * 128 + row) * 128 + ch * 8;
        bPtr[r] = t2T + ((size_t)n * 4096 + p0 + row) * 128 + ch * 8;
    }
    const int q = lane >> 4, fr = lane & 15;
    int aRd[2][4], bRd[2][4];
#pragma unroll
    for (int i = 0; i < 4; ++i) {
        int ra = wr * 64 + i * 16 + fr;
        int rb = wc * 64 + i * 16 + fr;
#pragma unroll
        for (int ks = 0; ks < 2; ++ks) {
            aRd[ks][i] = (ra * 8 + ((ks * 4 + q) ^ (ra & 7))) * 8;
            bRd[ks][i] = (rb * 8 + ((ks * 4 + q) ^ (rb & 7))) * 8;
        }
    }
    f32x4 acc[4][4] = {};
    for (int t = 0; t < 2; ++t) {
        s16x8 av[4], bv[4];
#pragma unroll
        for (int r = 0; r < 4; ++r) {
            av[r] = *(const s16x8*)aPtr[r];
            bv[r] = *(const s16x8*)bPtr[r];
            aPtr[r] += 64;
            bPtr[r] += 64;
        }
        __syncthreads();
#pragma unroll
        for (int r = 0; r < 4; ++r) {
            *(s16x8*)&As[off[r]] = av[r];
            *(s16x8*)&Bs[off[r]] = bv[r];
        }
        __syncthreads();
#pragma unroll
        for (int ks = 0; ks < 2; ++ks) {
            s16x8 a[4], b[4];
#pragma unroll
            for (int i = 0; i < 4; ++i) a[i] = *(const s16x8*)&As[aRd[ks][i]];
#pragma unroll
            for (int i = 0; i < 4; ++i) b[i] = *(const s16x8*)&Bs[bRd[ks][i]];
#pragma unroll
            for (int i = 0; i < 4; ++i)
#pragma unroll
                for (int j = 0; j < 4; ++j)
                    acc[i][j] = __builtin_amdgcn_mfma_f32_16x16x32_bf16(a[i], b[j], acc[i][j], 0, 0, 0);
        }
    }
    const float scale = 0.0192879257f;   // 1/sqrt(2688)
#pragma unroll
    for (int i = 0; i < 4; ++i) {
        int row = wr * 64 + i * 16 + q * 4;
#pragma unroll
        for (int j = 0; j < 4; ++j) {
            int col = wc * 64 + j * 16 + fr;
#pragma unroll
            for (int reg = 0; reg < 4; ++reg) {
                size_t oi = ((size_t)(n * 128 + row + reg)) * 4096 + p0 + col;
                out[oi] = fmaxf(out[oi], acc[i][j][reg] * scale);
            }
        }
    }
}

extern "C" void kernel_launch(void* const* d_in, const int* in_sizes, int n_in,
                              void* d_out, int out_size, void* d_ws, size_t ws_size,
                              hipStream_t stream) {
    const float* x   = (const float*)d_in[0];
    const float* p1  = (const float*)d_in[1];
    const float* p7  = (const float*)d_in[2];
    const float* p10 = (const float*)d_in[3];
    float* out = (float*)d_out;

    ushort_t* t1h  = (ushort_t*)d_ws;         // 4,194,304
    ushort_t* xTr  = t1h + 4194304;           // 4,194,304
    ushort_t* t2T  = xTr + 4194304;           // 4,194,304
    ushort_t* xp   = t2T + 4194304;           // 9,732,096
    ushort_t* p7h  = xp + 9732096;            // 16,384
    ushort_t* t11h = p7h + 16384;             // 8,257,536
    ushort_t* Uh   = t11h + 8257536;          // 131,072
    float*    wft  = (float*)(Uh + 131072);   // 344,064 f32

    xtr_prep<<<dim3(64, 2, 8), 256, 0, stream>>>(x, p1, t1h, xTr, t2T);
    xpgen_kernel<<<dim3(4752, 2), 256, 0, stream>>>(x, xp);
    wft_kernel<<<1344, 256, 0, stream>>>(p10, wft);
    pcast_kernel<<<16, 256, 0, stream>>>(p7, p7h);
    t7t12_mfma<<<dim3(32, 8), 256, 0, stream>>>(p7h, xTr, x, out);
    t11_mfma<<<dim3(21, 3, 8), 256, 0, stream>>>(t1h, xp, t11h);
    u_gemm_sparse<<<dim3(4, 64), 256, 0, stream>>>(t11h, wft, Uh);
    t13_mfma<<<dim3(32, 8), 256, 0, stream>>>(Uh, t2T, out);
}

// Round 4
// 84.745 us; speedup vs baseline: 5.5808x; 1.6387x over previous
//
#include <hip/hip_runtime.h>
#include <hip/hip_bf16.h>

typedef unsigned short ushort_t;
typedef unsigned int uint_t;
typedef __attribute__((ext_vector_type(8))) short s16x8;
typedef __attribute__((ext_vector_type(4))) float f32x4;
typedef __attribute__((ext_vector_type(4))) ushort_t u16x4;
typedef __attribute__((ext_vector_type(8))) ushort_t u16x8;

__device__ __forceinline__ ushort_t f2bf(float f) {
    uint_t u = __float_as_uint(f);
    uint_t r = (u + 0x7FFFu + ((u >> 16) & 1u)) >> 16;
    return (ushort_t)r;
}
__device__ __forceinline__ float bf2f(ushort_t u) {
    return __uint_as_float(((uint_t)u) << 16);
}
__device__ __forceinline__ s16x8 relu8(s16x8 v) {
    s16x8 r;
#pragma unroll
    for (int e = 0; e < 8; ++e) { short xv = v[e]; r[e] = (xv < 0) ? (short)0 : xv; }
    return r;
}

// ---- prep: t1h[c][p], t2T[p][c], xpTh[s(4752)][c] (padded transpose, interior) ----
// grid (64 y, 2 ctile, 8 n), 256 thr.
__global__ __launch_bounds__(256) void xtr_prep(const float* __restrict__ x,
                                                const float* __restrict__ p1,
                                                ushort_t* __restrict__ t1h,
                                                ushort_t* __restrict__ t2T,
                                                ushort_t* __restrict__ xpTh) {
    __shared__ float xs[64][65];
    __shared__ float p1s[64];
    const int y  = blockIdx.x;
    const int c0 = blockIdx.y * 64;
    const int n  = blockIdx.z;
    const int t  = threadIdx.x;
    if (t < 64) p1s[t] = p1[(c0 + t) * 64 + y];
#pragma unroll
    for (int cc = 0; cc < 4; ++cc) {
        int c = cc * 16 + (t >> 4);
        int px = (t & 15) * 4;
        float4 v = *(const float4*)(x + ((size_t)((n * 128 + c0 + c)) * 64 + y) * 64 + px);
        xs[c][px] = v.x; xs[c][px + 1] = v.y; xs[c][px + 2] = v.z; xs[c][px + 3] = v.w;
    }
    __syncthreads();
    {   // t1h natural layout
        int c = t >> 2, px0 = (t & 3) * 16;
        float pv = p1s[c];
        u16x8 o0, o1;
#pragma unroll
        for (int e = 0; e < 8; ++e) {
            o0[e] = f2bf(pv * xs[c][px0 + e]);
            o1[e] = f2bf(pv * xs[c][px0 + 8 + e]);
        }
        ushort_t* dst = t1h + (size_t)(n * 128 + c0 + c) * 4096 + y * 64 + px0;
        *(u16x8*)dst = o0;
        *(u16x8*)(dst + 8) = o1;
    }
    {   // transposed outputs: raw x -> xpTh (interior), t2 -> t2T
        int p = t >> 2, cx0 = (t & 3) * 16;
        u16x8 r0, r1, s0, s1;
#pragma unroll
        for (int e = 0; e < 8; ++e) {
            float v0 = xs[cx0 + e][p];
            float v1 = xs[cx0 + 8 + e][p];
            r0[e] = f2bf(v0);
            r1[e] = f2bf(v1);
            s0[e] = f2bf(v0 + p1s[cx0 + e] * v0);
            s1[e] = f2bf(v1 + p1s[cx0 + 8 + e] * v1);
        }
        size_t baseT = ((size_t)n * 4096 + y * 64 + p) * 128 + c0 + cx0;
        *(u16x8*)(t2T + baseT) = s0;
        *(u16x8*)(t2T + baseT + 8) = s1;
        size_t baseP = ((size_t)n * 4752 + (y + 1) * 72 + p + 3) * 128 + c0 + cx0;
        *(u16x8*)(xpTh + baseP) = r0;
        *(u16x8*)(xpTh + baseP + 8) = r1;
    }
}

// wfc[g][tap][j][c32] = bf16(p10[((32g+c32)*21+tap)*32 + j])
__global__ void wfc_gen(const float* __restrict__ p10, ushort_t* __restrict__ wfc) {
    int idx = blockIdx.x * 256 + threadIdx.x;   // < 86016
    int c32 = idx & 31;
    int j = (idx >> 5) & 31;
    int rest = idx >> 10;                       // g*21 + tap
    int tap = rest % 21, g = rest / 21;
    wfc[idx] = f2bf(p10[((32 * g + c32) * 21 + tap) * 32 + j]);
}

__global__ void pcast_kernel(const float* __restrict__ p7, ushort_t* __restrict__ p7h) {
    int i = (blockIdx.x * 256 + threadIdx.x) * 4;   // < 16384
    float4 v = *(const float4*)(p7 + i);
    u16x4 o; o[0] = f2bf(v.x); o[1] = f2bf(v.y); o[2] = f2bf(v.z); o[3] = f2bf(v.w);
    *(u16x4*)(p7h + i) = o;
}

// ---- fused t7 (MFMA, relu-on-load from xpTh) + t12 epilogue ----
// grid (32 ptiles, 8 n)
__global__ __launch_bounds__(256) void t7t12_mfma(const ushort_t* __restrict__ p7h,
                                                  const ushort_t* __restrict__ xpTh,
                                                  const float* __restrict__ x,
                                                  float* __restrict__ out) {
    __shared__ ushort_t sh[16384];
    ushort_t* As = sh;
    ushort_t* Bs = sh + 8192;
    const int p0 = blockIdx.x * 128;
    const int n  = blockIdx.y;
    const int tid = threadIdx.x;
    const int lane = tid & 63, wid = tid >> 6;
    const int wr = wid >> 1, wc = wid & 1;

    const ushort_t* aPtr[4];
    const ushort_t* bPtr[4];
    int off[4];
#pragma unroll
    for (int r = 0; r < 4; ++r) {
        int slot = r * 256 + tid;
        int row = slot >> 3, ch = slot & 7;
        off[r] = (row * 8 + (ch ^ (row & 7))) * 8;
        aPtr[r] = p7h + row * 128 + ch * 8;
        int prow = p0 + row;
        int srow = ((prow >> 6) + 1) * 72 + (prow & 63) + 3;
        bPtr[r] = xpTh + ((size_t)n * 4752 + srow) * 128 + ch * 8;
    }
    const int q = lane >> 4, fr = lane & 15;
    int aRd[2][4], bRd[2][4];
#pragma unroll
    for (int i = 0; i < 4; ++i) {
        int ra = wr * 64 + i * 16 + fr;
        int rb = wc * 64 + i * 16 + fr;
#pragma unroll
        for (int ks = 0; ks < 2; ++ks) {
            aRd[ks][i] = (ra * 8 + ((ks * 4 + q) ^ (ra & 7))) * 8;
            bRd[ks][i] = (rb * 8 + ((ks * 4 + q) ^ (rb & 7))) * 8;
        }
    }
    f32x4 acc[4][4] = {};
    for (int t = 0; t < 2; ++t) {
        s16x8 av[4], bv[4];
#pragma unroll
        for (int r = 0; r < 4; ++r) {
            av[r] = *(const s16x8*)aPtr[r];
            bv[r] = relu8(*(const s16x8*)bPtr[r]);
            aPtr[r] += 64;
            bPtr[r] += 64;
        }
        __syncthreads();
#pragma unroll
        for (int r = 0; r < 4; ++r) {
            *(s16x8*)&As[off[r]] = av[r];
            *(s16x8*)&Bs[off[r]] = bv[r];
        }
        __syncthreads();
#pragma unroll
        for (int ks = 0; ks < 2; ++ks) {
            s16x8 a[4], b[4];
#pragma unroll
            for (int i = 0; i < 4; ++i) a[i] = *(const s16x8*)&As[aRd[ks][i]];
#pragma unroll
            for (int i = 0; i < 4; ++i) b[i] = *(const s16x8*)&Bs[bRd[ks][i]];
#pragma unroll
            for (int i = 0; i < 4; ++i)
#pragma unroll
                for (int j = 0; j < 4; ++j)
                    acc[i][j] = __builtin_amdgcn_mfma_f32_16x16x32_bf16(a[i], b[j], acc[i][j], 0, 0, 0);
        }
    }
    // t12 epilogue
    ushort_t* Cs = sh;
    for (int pass = 0; pass < 2; ++pass) {
        __syncthreads();
        for (int i2 = tid; i2 < 4992; i2 += 256) ((uint_t*)Cs)[i2] = 0u;
        __syncthreads();
        if (wr == pass) {
#pragma unroll
            for (int i = 0; i < 4; ++i) {
                int row = i * 16 + q * 4;
#pragma unroll
                for (int j = 0; j < 4; ++j) {
                    int col = wc * 64 + j * 16 + fr;
                    int cbase = (col >> 6) * 78 + 6 + (col & 63);
#pragma unroll
                    for (int reg = 0; reg < 4; ++reg)
                        Cs[(row + reg) * 156 + cbase] = f2bf(acc[i][j][reg]);
                }
            }
        }
        __syncthreads();
        for (int rep = 0; rep < 32; ++rep) {
            int flat = rep * 256 + tid;
            int ol = flat >> 7;
            int pcol = flat & 127;
            int half = pcol >> 6, xx = pcol & 63;
            float s = 0.0f;
#pragma unroll
            for (int jj = 0; jj < 5; ++jj)
                s += bf2f(Cs[ol * 156 + half * 78 + xx + 3 * jj]);
            size_t oi = ((size_t)(n * 128 + pass * 64 + ol)) * 4096 + p0 + pcol;
            out[oi] = x[oi] - 0.2f * s;
        }
    }
}

// ---- G[p][j] grouped 3x7 conv via MFMA: Gh[n][32g+j][p] ----
// grid (16 ptiles, 4 g, 8 n), 256 thr (4 waves). M=32(j), N=256(p), K=21 taps x 32 ch.
__global__ __launch_bounds__(256) void g_mfma(const ushort_t* __restrict__ xpTh,
                                              const ushort_t* __restrict__ wfc,
                                              ushort_t* __restrict__ Gh) {
    __shared__ ushort_t As[1024];    // 32j x 32c, swizzled 2-entities/128B-row
    __shared__ ushort_t Bs[8192];    // 256p x 32c, same swizzle
    const int p0 = blockIdx.x * 256;
    const int g  = blockIdx.y;
    const int n  = blockIdx.z;
    const int tid = threadIdx.x;
    const int lane = tid & 63, wid = tid >> 6;
    const int q = lane >> 4, fr = lane & 15;
    const int y0 = p0 >> 6;
    const int syy = y0 + (tid >> 6);
    const int sxx = tid & 63;

    // swizzled offset (ushort units): entity e, chunk qq (8 bf16 per chunk)
    //   off = (e>>1)*64 + ((((e&1)<<2)|qq) ^ ((e>>1)&7))*8
    int aRd[2], bRd[4];
#pragma unroll
    for (int i = 0; i < 2; ++i) {
        int e = i * 16 + fr;
        aRd[i] = (e >> 1) * 64 + (((((e & 1) << 2) | q)) ^ ((e >> 1) & 7)) * 8;
    }
#pragma unroll
    for (int j = 0; j < 4; ++j) {
        int e = wid * 64 + j * 16 + fr;
        bRd[j] = (e >> 1) * 64 + (((((e & 1) << 2) | q)) ^ ((e >> 1) & 7)) * 8;
    }
    int bWr[4];
#pragma unroll
    for (int qq = 0; qq < 4; ++qq)
        bWr[qq] = (tid >> 1) * 64 + (((((tid & 1) << 2) | qq)) ^ ((tid >> 1) & 7)) * 8;
    int aWr = 0;
    if (tid < 128) {
        int e = tid >> 2, qq = tid & 3;
        aWr = (e >> 1) * 64 + (((((e & 1) << 2) | qq)) ^ ((e >> 1) & 7)) * 8;
    }
    const ushort_t* bSrcBase = xpTh + (size_t)n * 4752 * 128 + g * 32;

    f32x4 acc[2][4] = {};
    for (int tap = 0; tap < 21; ++tap) {
        int ki = tap / 7, kj = tap - ki * 7;
        const ushort_t* src = bSrcBase + (size_t)((syy + ki) * 72 + sxx + kj) * 128;
        u16x8 bv[4];
#pragma unroll
        for (int qq = 0; qq < 4; ++qq) bv[qq] = *(const u16x8*)(src + qq * 8);
        u16x8 av;
        if (tid < 128) av = *(const u16x8*)(wfc + (g * 21 + tap) * 1024 + tid * 8);
        __syncthreads();
#pragma unroll
        for (int qq = 0; qq < 4; ++qq) *(u16x8*)&Bs[bWr[qq]] = bv[qq];
        if (tid < 128) *(u16x8*)&As[aWr] = av;
        __syncthreads();
        s16x8 a[2], b[4];
#pragma unroll
        for (int i = 0; i < 2; ++i) a[i] = *(const s16x8*)&As[aRd[i]];
#pragma unroll
        for (int j = 0; j < 4; ++j) b[j] = *(const s16x8*)&Bs[bRd[j]];
#pragma unroll
        for (int i = 0; i < 2; ++i)
#pragma unroll
            for (int j = 0; j < 4; ++j)
                acc[i][j] = __builtin_amdgcn_mfma_f32_16x16x32_bf16(a[i], b[j], acc[i][j], 0, 0, 0);
    }
#pragma unroll
    for (int i = 0; i < 2; ++i) {
        int row = i * 16 + q * 4;
#pragma unroll
        for (int j = 0; j < 4; ++j) {
            int col = wid * 64 + j * 16 + fr;
            ushort_t* dst = Gh + ((size_t)n * 128 + 32 * g + row) * 4096 + p0 + col;
#pragma unroll
            for (int reg = 0; reg < 4; ++reg)
                dst[(size_t)reg * 4096] = f2bf(acc[i][j][reg]);
        }
    }
}

// ---- U partials: upart[(n,ks)][c][j] = sum_{p in chunk} t1h[c][p]*Gh[j][p] ----
// grid (8 ks, 8 n)
__global__ __launch_bounds__(256) void u_mfma(const ushort_t* __restrict__ t1h,
                                              const ushort_t* __restrict__ Gh,
                                              float* __restrict__ upart) {
    __shared__ ushort_t As[8192];
    __shared__ ushort_t Bs[8192];
    const int ks = blockIdx.x;
    const int n  = blockIdx.y;
    const int kbase = ks * 512;
    const int tid = threadIdx.x;
    const int lane = tid & 63, wid = tid >> 6;
    const int wr = wid >> 1, wc = wid & 1;
    const ushort_t* aPtr[4];
    const ushort_t* bPtr[4];
    int off[4];
#pragma unroll
    for (int r = 0; r < 4; ++r) {
        int slot = r * 256 + tid;
        int row = slot >> 3, ch = slot & 7;
        off[r] = (row * 8 + (ch ^ (row & 7))) * 8;
        aPtr[r] = t1h + (size_t)(n * 128 + row) * 4096 + kbase + ch * 8;
        bPtr[r] = Gh  + (size_t)(n * 128 + row) * 4096 + kbase + ch * 8;
    }
    const int q = lane >> 4, fr = lane & 15;
    int aRd[2][4], bRd[2][4];
#pragma unroll
    for (int i = 0; i < 4; ++i) {
        int ra = wr * 64 + i * 16 + fr;
        int rb = wc * 64 + i * 16 + fr;
#pragma unroll
        for (int ks2 = 0; ks2 < 2; ++ks2) {
            aRd[ks2][i] = (ra * 8 + ((ks2 * 4 + q) ^ (ra & 7))) * 8;
            bRd[ks2][i] = (rb * 8 + ((ks2 * 4 + q) ^ (rb & 7))) * 8;
        }
    }
    f32x4 acc[4][4] = {};
    for (int t = 0; t < 8; ++t) {
        s16x8 av[4], bv[4];
#pragma unroll
        for (int r = 0; r < 4; ++r) {
            av[r] = *(const s16x8*)aPtr[r];
            bv[r] = *(const s16x8*)bPtr[r];
            aPtr[r] += 64;
            bPtr[r] += 64;
        }
        __syncthreads();
#pragma unroll
        for (int r = 0; r < 4; ++r) {
            *(s16x8*)&As[off[r]] = av[r];
            *(s16x8*)&Bs[off[r]] = bv[r];
        }
        __syncthreads();
#pragma unroll
        for (int ks2 = 0; ks2 < 2; ++ks2) {
            s16x8 a[4], b[4];
#pragma unroll
            for (int i = 0; i < 4; ++i) a[i] = *(const s16x8*)&As[aRd[ks2][i]];
#pragma unroll
            for (int i = 0; i < 4; ++i) b[i] = *(const s16x8*)&Bs[bRd[ks2][i]];
#pragma unroll
            for (int i = 0; i < 4; ++i)
#pragma unroll
                for (int j = 0; j < 4; ++j)
                    acc[i][j] = __builtin_amdgcn_mfma_f32_16x16x32_bf16(a[i], b[j], acc[i][j], 0, 0, 0);
        }
    }
#pragma unroll
    for (int i = 0; i < 4; ++i) {
        int row = wr * 64 + i * 16 + q * 4;
#pragma unroll
        for (int j = 0; j < 4; ++j) {
            int col = wc * 64 + j * 16 + fr;
            float* dp = upart + ((size_t)(n * 8 + ks) * 128 + row) * 128 + col;
#pragma unroll
            for (int reg = 0; reg < 4; ++reg)
                dp[(size_t)reg * 128] = acc[i][j][reg];
        }
    }
}

__global__ void ureduce_kernel(const float* __restrict__ upart, ushort_t* __restrict__ Uh) {
    int idx = blockIdx.x * 256 + threadIdx.x;   // < 131072
    int n = idx >> 14, rc = idx & 16383;
    float s = 0.0f;
#pragma unroll
    for (int k = 0; k < 8; ++k) s += upart[(size_t)((n * 8 + k) << 14) + rc];
    Uh[idx] = f2bf(s * 0.015625f);               // 1/64
}

// ---- t13: out = max(out, scale * Uh . t2T^T). grid (32 ptiles, 8 n) ----
__global__ __launch_bounds__(256) void t13_mfma(const ushort_t* __restrict__ Uh,
                                                const ushort_t* __restrict__ t2T,
                                                float* __restrict__ out) {
    __shared__ ushort_t As[8192];
    __shared__ ushort_t Bs[8192];
    const int p0 = blockIdx.x * 128;
    const int n  = blockIdx.y;
    const int tid = threadIdx.x;
    const int lane = tid & 63, wid = tid >> 6;
    const int wr = wid >> 1, wc = wid & 1;
    const ushort_t* aPtr[4];
    const ushort_t* bPtr[4];
    int off[4];
#pragma unroll
    for (int r = 0; r < 4; ++r) {
        int slot = r * 256 + tid;
        int row = slot >> 3, ch = slot & 7;
        off[r] = (row * 8 + (ch ^ (row & 7))) * 8;
        aPtr[r] = Uh + ((size_t)n * 128 + row) * 128 + ch * 8;
        bPtr[r] = t2T + ((size_t)n * 4096 + p0 + row) * 128 + ch * 8;
    }
    const int q = lane >> 4, fr = lane & 15;
    int aRd[2][4], bRd[2][4];
#pragma unroll
    for (int i = 0; i < 4; ++i) {
        int ra = wr * 64 + i * 16 + fr;
        int rb = wc * 64 + i * 16 + fr;
#pragma unroll
        for (int ks = 0; ks < 2; ++ks) {
            aRd[ks][i] = (ra * 8 + ((ks * 4 + q) ^ (ra & 7))) * 8;
            bRd[ks][i] = (rb * 8 + ((ks * 4 + q) ^ (rb & 7))) * 8;
        }
    }
    f32x4 acc[4][4] = {};
    for (int t = 0; t < 2; ++t) {
        s16x8 av[4], bv[4];
#pragma unroll
        for (int r = 0; r < 4; ++r) {
            av[r] = *(const s16x8*)aPtr[r];
            bv[r] = *(const s16x8*)bPtr[r];
            aPtr[r] += 64;
            bPtr[r] += 64;
        }
        __syncthreads();
#pragma unroll
        for (int r = 0; r < 4; ++r) {
            *(s16x8*)&As[off[r]] = av[r];
            *(s16x8*)&Bs[off[r]] = bv[r];
        }
        __syncthreads();
#pragma unroll
        for (int ks = 0; ks < 2; ++ks) {
            s16x8 a[4], b[4];
#pragma unroll
            for (int i = 0; i < 4; ++i) a[i] = *(const s16x8*)&As[aRd[ks][i]];
#pragma unroll
            for (int i = 0; i < 4; ++i) b[i] = *(const s16x8*)&Bs[bRd[ks][i]];
#pragma unroll
            for (int i = 0; i < 4; ++i)
#pragma unroll
                for (int j = 0; j < 4; ++j)
                    acc[i][j] = __builtin_amdgcn_mfma_f32_16x16x32_bf16(a[i], b[j], acc[i][j], 0, 0, 0);
        }
    }
    const float scale = 0.0192879257f;   // 1/sqrt(2688)
#pragma unroll
    for (int i = 0; i < 4; ++i) {
        int row = wr * 64 + i * 16 + q * 4;
#pragma unroll
        for (int j = 0; j < 4; ++j) {
            int col = wc * 64 + j * 16 + fr;
#pragma unroll
            for (int reg = 0; reg < 4; ++reg) {
                size_t oi = ((size_t)(n * 128 + row + reg)) * 4096 + p0 + col;
                out[oi] = fmaxf(out[oi], acc[i][j][reg] * scale);
            }
        }
    }
}

extern "C" void kernel_launch(void* const* d_in, const int* in_sizes, int n_in,
                              void* d_out, int out_size, void* d_ws, size_t ws_size,
                              hipStream_t stream) {
    const float* x   = (const float*)d_in[0];
    const float* p1  = (const float*)d_in[1];
    const float* p7  = (const float*)d_in[2];
    const float* p10 = (const float*)d_in[3];
    float* out = (float*)d_out;

    ushort_t* t1h  = (ushort_t*)d_ws;          // 4,194,304
    ushort_t* t2T  = t1h + 4194304;            // 4,194,304
    ushort_t* xpTh = t2T + 4194304;            // 4,866,048
    ushort_t* p7h  = xpTh + 4866048;           // 16,384
    ushort_t* Gh   = p7h + 16384;              // 4,194,304
    ushort_t* wfc  = Gh + 4194304;             // 86,016
    ushort_t* Uh   = wfc + 86016;              // 131,072
    float*    upart = (float*)(Uh + 131072);   // 1,048,576 f32

    hipMemsetAsync(xpTh, 0, (size_t)4866048 * 2, stream);

    xtr_prep<<<dim3(64, 2, 8), 256, 0, stream>>>(x, p1, t1h, t2T, xpTh);
    wfc_gen<<<336, 256, 0, stream>>>(p10, wfc);
    pcast_kernel<<<16, 256, 0, stream>>>(p7, p7h);
    t7t12_mfma<<<dim3(32, 8), 256, 0, stream>>>(p7h, xpTh, x, out);
    g_mfma<<<dim3(16, 4, 8), 256, 0, stream>>>(xpTh, wfc, Gh);
    u_mfma<<<dim3(8, 8), 256, 0, stream>>>(t1h, Gh, upart);
    ureduce_kernel<<<512, 256, 0, stream>>>(upart, Uh);
    t13_mfma<<<dim3(32, 8), 256, 0, stream>>>(Uh, t2T, out);
}

// Round 5
// 84.564 us; speedup vs baseline: 5.5926x; 1.0021x over previous
//
#include <hip/hip_runtime.h>
#include <hip/hip_bf16.h>

typedef unsigned short ushort_t;
typedef unsigned int uint_t;
typedef __attribute__((ext_vector_type(8))) short s16x8;
typedef __attribute__((ext_vector_type(4))) float f32x4;
typedef __attribute__((ext_vector_type(4))) ushort_t u16x4;
typedef __attribute__((ext_vector_type(8))) ushort_t u16x8;

__device__ __forceinline__ ushort_t f2bf(float f) {
    uint_t u = __float_as_uint(f);
    uint_t r = (u + 0x7FFFu + ((u >> 16) & 1u)) >> 16;
    return (ushort_t)r;
}
__device__ __forceinline__ float bf2f(ushort_t u) {
    return __uint_as_float(((uint_t)u) << 16);
}
__device__ __forceinline__ s16x8 relu8(s16x8 v) {
    s16x8 r;
#pragma unroll
    for (int e = 0; e < 8; ++e) { short xv = v[e]; r[e] = (xv < 0) ? (short)0 : xv; }
    return r;
}

// zero xpTh (9,732,096 bytes = 608,256 uint4)
__global__ void zero_kernel(uint4* __restrict__ p) {
    int i = blockIdx.x * 256 + threadIdx.x;
    if (i < 608256) p[i] = make_uint4(0u, 0u, 0u, 0u);
}

// ---- prep: t1h[c][p], t2T[p][c], xpTh[s(4752)][c] (padded transpose, interior) ----
// grid (64 y, 2 ctile, 8 n), 256 thr.
__global__ __launch_bounds__(256) void xtr_prep(const float* __restrict__ x,
                                                const float* __restrict__ p1,
                                                ushort_t* __restrict__ t1h,
                                                ushort_t* __restrict__ t2T,
                                                ushort_t* __restrict__ xpTh) {
    __shared__ float xs[64][65];
    __shared__ float p1s[64];
    const int y  = blockIdx.x;
    const int c0 = blockIdx.y * 64;
    const int n  = blockIdx.z;
    const int t  = threadIdx.x;
    if (t < 64) p1s[t] = p1[(c0 + t) * 64 + y];
#pragma unroll
    for (int cc = 0; cc < 4; ++cc) {
        int c = cc * 16 + (t >> 4);
        int px = (t & 15) * 4;
        float4 v = *(const float4*)(x + ((size_t)((n * 128 + c0 + c)) * 64 + y) * 64 + px);
        xs[c][px] = v.x; xs[c][px + 1] = v.y; xs[c][px + 2] = v.z; xs[c][px + 3] = v.w;
    }
    __syncthreads();
    {   // t1h natural layout
        int c = t >> 2, px0 = (t & 3) * 16;
        float pv = p1s[c];
        u16x8 o0, o1;
#pragma unroll
        for (int e = 0; e < 8; ++e) {
            o0[e] = f2bf(pv * xs[c][px0 + e]);
            o1[e] = f2bf(pv * xs[c][px0 + 8 + e]);
        }
        ushort_t* dst = t1h + (size_t)(n * 128 + c0 + c) * 4096 + y * 64 + px0;
        *(u16x8*)dst = o0;
        *(u16x8*)(dst + 8) = o1;
    }
    {   // transposed outputs: raw x -> xpTh (interior), t2 -> t2T
        int p = t >> 2, cx0 = (t & 3) * 16;
        u16x8 r0, r1, s0, s1;
#pragma unroll
        for (int e = 0; e < 8; ++e) {
            float v0 = xs[cx0 + e][p];
            float v1 = xs[cx0 + 8 + e][p];
            r0[e] = f2bf(v0);
            r1[e] = f2bf(v1);
            s0[e] = f2bf(v0 + p1s[cx0 + e] * v0);
            s1[e] = f2bf(v1 + p1s[cx0 + 8 + e] * v1);
        }
        size_t baseT = ((size_t)n * 4096 + y * 64 + p) * 128 + c0 + cx0;
        *(u16x8*)(t2T + baseT) = s0;
        *(u16x8*)(t2T + baseT + 8) = s1;
        size_t baseP = ((size_t)n * 4752 + (y + 1) * 72 + p + 3) * 128 + c0 + cx0;
        *(u16x8*)(xpTh + baseP) = r0;
        *(u16x8*)(xpTh + baseP + 8) = r1;
    }
}

// wfc[g][tap][j][c32] = bf16(p10[((32g+c32)*21+tap)*32 + j])
__global__ void wfc_gen(const float* __restrict__ p10, ushort_t* __restrict__ wfc) {
    int idx = blockIdx.x * 256 + threadIdx.x;   // < 86016
    int c32 = idx & 31;
    int j = (idx >> 5) & 31;
    int rest = idx >> 10;                       // g*21 + tap
    int tap = rest % 21, g = rest / 21;
    wfc[idx] = f2bf(p10[((32 * g + c32) * 21 + tap) * 32 + j]);
}

__global__ void pcast_kernel(const float* __restrict__ p7, ushort_t* __restrict__ p7h) {
    int i = (blockIdx.x * 256 + threadIdx.x) * 4;   // < 16384
    float4 v = *(const float4*)(p7 + i);
    u16x4 o; o[0] = f2bf(v.x); o[1] = f2bf(v.y); o[2] = f2bf(v.z); o[3] = f2bf(v.w);
    *(u16x4*)(p7h + i) = o;
}

// ---- fused t7 (MFMA, relu-on-load from xpTh) + t12 epilogue ----
// grid (32 ptiles, 8 n)
__global__ __launch_bounds__(256) void t7t12_mfma(const ushort_t* __restrict__ p7h,
                                                  const ushort_t* __restrict__ xpTh,
                                                  const float* __restrict__ x,
                                                  float* __restrict__ out) {
    __shared__ ushort_t sh[16384];
    ushort_t* As = sh;
    ushort_t* Bs = sh + 8192;
    const int p0 = blockIdx.x * 128;
    const int n  = blockIdx.y;
    const int tid = threadIdx.x;
    const int lane = tid & 63, wid = tid >> 6;
    const int wr = wid >> 1, wc = wid & 1;

    const ushort_t* aPtr[4];
    const ushort_t* bPtr[4];
    int off[4];
#pragma unroll
    for (int r = 0; r < 4; ++r) {
        int slot = r * 256 + tid;
        int row = slot >> 3, ch = slot & 7;
        off[r] = (row * 8 + (ch ^ (row & 7))) * 8;
        aPtr[r] = p7h + row * 128 + ch * 8;
        int prow = p0 + row;
        int srow = ((prow >> 6) + 1) * 72 + (prow & 63) + 3;
        bPtr[r] = xpTh + ((size_t)n * 4752 + srow) * 128 + ch * 8;
    }
    const int q = lane >> 4, fr = lane & 15;
    int aRd[2][4], bRd[2][4];
#pragma unroll
    for (int i = 0; i < 4; ++i) {
        int ra = wr * 64 + i * 16 + fr;
        int rb = wc * 64 + i * 16 + fr;
#pragma unroll
        for (int ks = 0; ks < 2; ++ks) {
            aRd[ks][i] = (ra * 8 + ((ks * 4 + q) ^ (ra & 7))) * 8;
            bRd[ks][i] = (rb * 8 + ((ks * 4 + q) ^ (rb & 7))) * 8;
        }
    }
    f32x4 acc[4][4] = {};
    for (int t = 0; t < 2; ++t) {
        s16x8 av[4], bv[4];
#pragma unroll
        for (int r = 0; r < 4; ++r) {
            av[r] = *(const s16x8*)aPtr[r];
            bv[r] = relu8(*(const s16x8*)bPtr[r]);
            aPtr[r] += 64;
            bPtr[r] += 64;
        }
        __syncthreads();
#pragma unroll
        for (int r = 0; r < 4; ++r) {
            *(s16x8*)&As[off[r]] = av[r];
            *(s16x8*)&Bs[off[r]] = bv[r];
        }
        __syncthreads();
#pragma unroll
        for (int ks = 0; ks < 2; ++ks) {
            s16x8 a[4], b[4];
#pragma unroll
            for (int i = 0; i < 4; ++i) a[i] = *(const s16x8*)&As[aRd[ks][i]];
#pragma unroll
            for (int i = 0; i < 4; ++i) b[i] = *(const s16x8*)&Bs[bRd[ks][i]];
#pragma unroll
            for (int i = 0; i < 4; ++i)
#pragma unroll
                for (int j = 0; j < 4; ++j)
                    acc[i][j] = __builtin_amdgcn_mfma_f32_16x16x32_bf16(a[i], b[j], acc[i][j], 0, 0, 0);
        }
    }
    // t12 epilogue
    ushort_t* Cs = sh;
    for (int pass = 0; pass < 2; ++pass) {
        __syncthreads();
        for (int i2 = tid; i2 < 4992; i2 += 256) ((uint_t*)Cs)[i2] = 0u;
        __syncthreads();
        if (wr == pass) {
#pragma unroll
            for (int i = 0; i < 4; ++i) {
                int row = i * 16 + q * 4;
#pragma unroll
                for (int j = 0; j < 4; ++j) {
                    int col = wc * 64 + j * 16 + fr;
                    int cbase = (col >> 6) * 78 + 6 + (col & 63);
#pragma unroll
                    for (int reg = 0; reg < 4; ++reg)
                        Cs[(row + reg) * 156 + cbase] = f2bf(acc[i][j][reg]);
                }
            }
        }
        __syncthreads();
        for (int rep = 0; rep < 32; ++rep) {
            int flat = rep * 256 + tid;
            int ol = flat >> 7;
            int pcol = flat & 127;
            int half = pcol >> 6, xx = pcol & 63;
            float s = 0.0f;
#pragma unroll
            for (int jj = 0; jj < 5; ++jj)
                s += bf2f(Cs[ol * 156 + half * 78 + xx + 3 * jj]);
            size_t oi = ((size_t)(n * 128 + pass * 64 + ol)) * 4096 + p0 + pcol;
            out[oi] = x[oi] - 0.2f * s;
        }
    }
}

// ---- G[p][j] grouped 3x7 conv via MFMA: Gh[n][32g+j][p] ----
// grid (16 ptiles, 4 g, 8 n), 256 thr (4 waves). M=32(j), N=256(p), K=21 taps x 32 ch.
__global__ __launch_bounds__(256) void g_mfma(const ushort_t* __restrict__ xpTh,
                                              const ushort_t* __restrict__ wfc,
                                              ushort_t* __restrict__ Gh) {
    __shared__ ushort_t As[1024];    // 32j x 32c, swizzled 2-entities/128B-row
    __shared__ ushort_t Bs[8192];    // 256p x 32c, same swizzle
    const int p0 = blockIdx.x * 256;
    const int g  = blockIdx.y;
    const int n  = blockIdx.z;
    const int tid = threadIdx.x;
    const int lane = tid & 63, wid = tid >> 6;
    const int q = lane >> 4, fr = lane & 15;
    const int y0 = p0 >> 6;
    const int syy = y0 + (tid >> 6);
    const int sxx = tid & 63;

    int aRd[2], bRd[4];
#pragma unroll
    for (int i = 0; i < 2; ++i) {
        int e = i * 16 + fr;
        aRd[i] = (e >> 1) * 64 + (((((e & 1) << 2) | q)) ^ ((e >> 1) & 7)) * 8;
    }
#pragma unroll
    for (int j = 0; j < 4; ++j) {
        int e = wid * 64 + j * 16 + fr;
        bRd[j] = (e >> 1) * 64 + (((((e & 1) << 2) | q)) ^ ((e >> 1) & 7)) * 8;
    }
    int bWr[4];
#pragma unroll
    for (int qq = 0; qq < 4; ++qq)
        bWr[qq] = (tid >> 1) * 64 + (((((tid & 1) << 2) | qq)) ^ ((tid >> 1) & 7)) * 8;
    int aWr = 0;
    if (tid < 128) {
        int e = tid >> 2, qq = tid & 3;
        aWr = (e >> 1) * 64 + (((((e & 1) << 2) | qq)) ^ ((e >> 1) & 7)) * 8;
    }
    const ushort_t* bSrcBase = xpTh + (size_t)n * 4752 * 128 + g * 32;

    f32x4 acc[2][4] = {};
    for (int tap = 0; tap < 21; ++tap) {
        int ki = tap / 7, kj = tap - ki * 7;
        const ushort_t* src = bSrcBase + (size_t)((syy + ki) * 72 + sxx + kj) * 128;
        u16x8 bv[4];
#pragma unroll
        for (int qq = 0; qq < 4; ++qq) bv[qq] = *(const u16x8*)(src + qq * 8);
        u16x8 av;
        if (tid < 128) av = *(const u16x8*)(wfc + (g * 21 + tap) * 1024 + tid * 8);
        __syncthreads();
#pragma unroll
        for (int qq = 0; qq < 4; ++qq) *(u16x8*)&Bs[bWr[qq]] = bv[qq];
        if (tid < 128) *(u16x8*)&As[aWr] = av;
        __syncthreads();
        s16x8 a[2], b[4];
#pragma unroll
        for (int i = 0; i < 2; ++i) a[i] = *(const s16x8*)&As[aRd[i]];
#pragma unroll
        for (int j = 0; j < 4; ++j) b[j] = *(const s16x8*)&Bs[bRd[j]];
#pragma unroll
        for (int i = 0; i < 2; ++i)
#pragma unroll
            for (int j = 0; j < 4; ++j)
                acc[i][j] = __builtin_amdgcn_mfma_f32_16x16x32_bf16(a[i], b[j], acc[i][j], 0, 0, 0);
    }
#pragma unroll
    for (int i = 0; i < 2; ++i) {
        int row = i * 16 + q * 4;
#pragma unroll
        for (int j = 0; j < 4; ++j) {
            int col = wid * 64 + j * 16 + fr;
            ushort_t* dst = Gh + ((size_t)n * 128 + 32 * g + row) * 4096 + p0 + col;
#pragma unroll
            for (int reg = 0; reg < 4; ++reg)
                dst[(size_t)reg * 4096] = f2bf(acc[i][j][reg]);
        }
    }
}

// ---- U partials: upart[(n,ks)][c][j] = sum_{p in chunk} t1h[c][p]*Gh[j][p] ----
// grid (8 ks, 8 n)
__global__ __launch_bounds__(256) void u_mfma(const ushort_t* __restrict__ t1h,
                                              const ushort_t* __restrict__ Gh,
                                              float* __restrict__ upart) {
    __shared__ ushort_t As[8192];
    __shared__ ushort_t Bs[8192];
    const int ks = blockIdx.x;
    const int n  = blockIdx.y;
    const int kbase = ks * 512;
    const int tid = threadIdx.x;
    const int lane = tid & 63, wid = tid >> 6;
    const int wr = wid >> 1, wc = wid & 1;
    const ushort_t* aPtr[4];
    const ushort_t* bPtr[4];
    int off[4];
#pragma unroll
    for (int r = 0; r < 4; ++r) {
        int slot = r * 256 + tid;
        int row = slot >> 3, ch = slot & 7;
        off[r] = (row * 8 + (ch ^ (row & 7))) * 8;
        aPtr[r] = t1h + (size_t)(n * 128 + row) * 4096 + kbase + ch * 8;
        bPtr[r] = Gh  + (size_t)(n * 128 + row) * 4096 + kbase + ch * 8;
    }
    const int q = lane >> 4, fr = lane & 15;
    int aRd[2][4], bRd[2][4];
#pragma unroll
    for (int i = 0; i < 4; ++i) {
        int ra = wr * 64 + i * 16 + fr;
        int rb = wc * 64 + i * 16 + fr;
#pragma unroll
        for (int ks2 = 0; ks2 < 2; ++ks2) {
            aRd[ks2][i] = (ra * 8 + ((ks2 * 4 + q) ^ (ra & 7))) * 8;
            bRd[ks2][i] = (rb * 8 + ((ks2 * 4 + q) ^ (rb & 7))) * 8;
        }
    }
    f32x4 acc[4][4] = {};
    for (int t = 0; t < 8; ++t) {
        s16x8 av[4], bv[4];
#pragma unroll
        for (int r = 0; r < 4; ++r) {
            av[r] = *(const s16x8*)aPtr[r];
            bv[r] = *(const s16x8*)bPtr[r];
            aPtr[r] += 64;
            bPtr[r] += 64;
        }
        __syncthreads();
#pragma unroll
        for (int r = 0; r < 4; ++r) {
            *(s16x8*)&As[off[r]] = av[r];
            *(s16x8*)&Bs[off[r]] = bv[r];
        }
        __syncthreads();
#pragma unroll
        for (int ks2 = 0; ks2 < 2; ++ks2) {
            s16x8 a[4], b[4];
#pragma unroll
            for (int i = 0; i < 4; ++i) a[i] = *(const s16x8*)&As[aRd[ks2][i]];
#pragma unroll
            for (int i = 0; i < 4; ++i) b[i] = *(const s16x8*)&Bs[bRd[ks2][i]];
#pragma unroll
            for (int i = 0; i < 4; ++i)
#pragma unroll
                for (int j = 0; j < 4; ++j)
                    acc[i][j] = __builtin_amdgcn_mfma_f32_16x16x32_bf16(a[i], b[j], acc[i][j], 0, 0, 0);
        }
    }
#pragma unroll
    for (int i = 0; i < 4; ++i) {
        int row = wr * 64 + i * 16 + q * 4;
#pragma unroll
        for (int j = 0; j < 4; ++j) {
            int col = wc * 64 + j * 16 + fr;
            float* dp = upart + ((size_t)(n * 8 + ks) * 128 + row) * 128 + col;
#pragma unroll
            for (int reg = 0; reg < 4; ++reg)
                dp[(size_t)reg * 128] = acc[i][j][reg];
        }
    }
}

__global__ void ureduce_kernel(const float* __restrict__ upart, ushort_t* __restrict__ Uh) {
    int idx = blockIdx.x * 256 + threadIdx.x;   // < 131072
    int n = idx >> 14, rc = idx & 16383;
    float s = 0.0f;
#pragma unroll
    for (int k = 0; k < 8; ++k) s += upart[(size_t)((n * 8 + k) << 14) + rc];
    Uh[idx] = f2bf(s * 0.015625f);               // 1/64
}

// ---- t13: out = max(out, scale * Uh . t2T^T). grid (32 ptiles, 8 n) ----
__global__ __launch_bounds__(256) void t13_mfma(const ushort_t* __restrict__ Uh,
                                                const ushort_t* __restrict__ t2T,
                                                float* __restrict__ out) {
    __shared__ ushort_t As[8192];
    __shared__ ushort_t Bs[8192];
    const int p0 = blockIdx.x * 128;
    const int n  = blockIdx.y;
    const int tid = threadIdx.x;
    const int lane = tid & 63, wid = tid >> 6;
    const int wr = wid >> 1, wc = wid & 1;
    const ushort_t* aPtr[4];
    const ushort_t* bPtr[4];
    int off[4];
#pragma unroll
    for (int r = 0; r < 4; ++r) {
        int slot = r * 256 + tid;
        int row = slot >> 3, ch = slot & 7;
        off[r] = (row * 8 + (ch ^ (row & 7))) * 8;
        aPtr[r] = Uh + ((size_t)n * 128 + row) * 128 + ch * 8;
        bPtr[r] = t2T + ((size_t)n * 4096 + p0 + row) * 128 + ch * 8;
    }
    const int q = lane >> 4, fr = lane & 15;
    int aRd[2][4], bRd[2][4];
#pragma unroll
    for (int i = 0; i < 4; ++i) {
        int ra = wr * 64 + i * 16 + fr;
        int rb = wc * 64 + i * 16 + fr;
#pragma unroll
        for (int ks = 0; ks < 2; ++ks) {
            aRd[ks][i] = (ra * 8 + ((ks * 4 + q) ^ (ra & 7))) * 8;
            bRd[ks][i] = (rb * 8 + ((ks * 4 + q) ^ (rb & 7))) * 8;
        }
    }
    f32x4 acc[4][4] = {};
    for (int t = 0; t < 2; ++t) {
        s16x8 av[4], bv[4];
#pragma unroll
        for (int r = 0; r < 4; ++r) {
            av[r] = *(const s16x8*)aPtr[r];
            bv[r] = *(const s16x8*)bPtr[r];
            aPtr[r] += 64;
            bPtr[r] += 64;
        }
        __syncthreads();
#pragma unroll
        for (int r = 0; r < 4; ++r) {
            *(s16x8*)&As[off[r]] = av[r];
            *(s16x8*)&Bs[off[r]] = bv[r];
        }
        __syncthreads();
#pragma unroll
        for (int ks = 0; ks < 2; ++ks) {
            s16x8 a[4], b[4];
#pragma unroll
            for (int i = 0; i < 4; ++i) a[i] = *(const s16x8*)&As[aRd[ks][i]];
#pragma unroll
            for (int i = 0; i < 4; ++i) b[i] = *(const s16x8*)&Bs[bRd[ks][i]];
#pragma unroll
            for (int i = 0; i < 4; ++i)
#pragma unroll
                for (int j = 0; j < 4; ++j)
                    acc[i][j] = __builtin_amdgcn_mfma_f32_16x16x32_bf16(a[i], b[j], acc[i][j], 0, 0, 0);
        }
    }
    const float scale = 0.0192879257f;   // 1/sqrt(2688)
#pragma unroll
    for (int i = 0; i < 4; ++i) {
        int row = wr * 64 + i * 16 + q * 4;
#pragma unroll
        for (int j = 0; j < 4; ++j) {
            int col = wc * 64 + j * 16 + fr;
#pragma unroll
            for (int reg = 0; reg < 4; ++reg) {
                size_t oi = ((size_t)(n * 128 + row + reg)) * 4096 + p0 + col;
                out[oi] = fmaxf(out[oi], acc[i][j][reg] * scale);
            }
        }
    }
}

extern "C" void kernel_launch(void* const* d_in, const int* in_sizes, int n_in,
                              void* d_out, int out_size, void* d_ws, size_t ws_size,
                              hipStream_t stream) {
    const float* x   = (const float*)d_in[0];
    const float* p1  = (const float*)d_in[1];
    const float* p7  = (const float*)d_in[2];
    const float* p10 = (const float*)d_in[3];
    float* out = (float*)d_out;

    ushort_t* t1h  = (ushort_t*)d_ws;          // 4,194,304
    ushort_t* t2T  = t1h + 4194304;            // 4,194,304
    ushort_t* xpTh = t2T + 4194304;            // 4,866,048
    ushort_t* p7h  = xpTh + 4866048;           // 16,384
    ushort_t* Gh   = p7h + 16384;              // 4,194,304
    ushort_t* wfc  = Gh + 4194304;             // 86,016
    ushort_t* Uh   = wfc + 86016;              // 131,072
    float*    upart = (float*)(Uh + 131072);   // 1,048,576 f32

    zero_kernel<<<2376, 256, 0, stream>>>((uint4*)xpTh);
    xtr_prep<<<dim3(64, 2, 8), 256, 0, stream>>>(x, p1, t1h, t2T, xpTh);
    wfc_gen<<<336, 256, 0, stream>>>(p10, wfc);
    pcast_kernel<<<16, 256, 0, stream>>>(p7, p7h);
    t7t12_mfma<<<dim3(32, 8), 256, 0, stream>>>(p7h, xpTh, x, out);
    g_mfma<<<dim3(16, 4, 8), 256, 0, stream>>>(xpTh, wfc, Gh);
    u_mfma<<<dim3(8, 8), 256, 0, stream>>>(t1h, Gh, upart);
    ureduce_kernel<<<512, 256, 0, stream>>>(upart, Uh);
    t13_mfma<<<dim3(32, 8), 256, 0, stream>>>(Uh, t2T, out);
}